// Round 16
// baseline (359.486 us; speedup 1.0000x reference)
//
#include <hip/hip_runtime.h>
#include <hip/hip_bf16.h>

// Graph message-passing layer, bf16 MFMA implementation, v16.
// vs v15: REVERT the 2-chunk pipeline (VGPR 128->164 halved occupancy; edge
// 94->150us). Instead cut per-wave registers: U stored/held in bf16 (32->16
// regs) and __launch_bounds__(256,4) on the edge kernel to fit 4 waves/SIMD
// on the unified VGPR+AGPR file. Dataflow = v14 (verified).
// N=10000, E=640000, F=M=O=128.

#define NN 10000
#define NE 640000
#define BINW 160

typedef __attribute__((ext_vector_type(8))) short short8;
typedef __attribute__((ext_vector_type(4))) short short4v;
typedef __attribute__((ext_vector_type(4))) float floatx4;

__device__ __forceinline__ short bfc(float f) {
    __hip_bfloat16 h = __float2bfloat16(f);
    return *reinterpret_cast<short*>(&h);
}
__device__ __forceinline__ float bf2f(short s) {
    union { unsigned u; float f; } v; v.u = ((unsigned)(unsigned short)s) << 16;
    return v.f;
}

__device__ __forceinline__ float sigmoidf_(float x) {
    return __builtin_amdgcn_rcpf(1.f + __expf(-x));
}
__device__ __forceinline__ float softsignf_(float x) {
    return x * __builtin_amdgcn_rcpf(1.f + fabsf(x));
}

// ---------- fused prep kernel ----------
// partitions: [0,2500) edge binning | [2500,2628) WuvT | [2628,2692) W2T
// | [2692,2884) Wf1T | [2884,2948) Wf2T
__global__ __launch_bounds__(256) void prep_all(
    const int* __restrict__ rows, const int* __restrict__ cols,
    const float* __restrict__ Wm1, const float* __restrict__ Wm2,
    const float* __restrict__ Wf1, const float* __restrict__ Wf2,
    short* __restrict__ WuvT, short* __restrict__ W2T,
    short* __restrict__ Wf1T, short* __restrict__ Wf2T,
    int* __restrict__ counts, unsigned short* __restrict__ ecbin)
{
    const int bid = blockIdx.x, tid = threadIdx.x;
    if (bid < 2500) {                       // bin edges by source node (640000, exact)
        int e = bid * 256 + tid;
        int r = rows[e];
        int p = atomicAdd(&counts[r], 1);
        if (p < BINW) ecbin[r * BINW + p] = (unsigned short)cols[e];
    } else if (bid < 2628) {                // WuvT[256][128]: c<128 -> W1a^T else W1b^T
        int i = (bid - 2500) * 256 + tid;   // 32768, exact
        int c = i >> 7, k = i & 127;
        WuvT[i] = bfc(Wm1[(k + ((c >> 7) << 7)) * 128 + (c & 127)]);
    } else if (bid < 2692) {                // Wm2 [128][128] -> plain T [m][k]
        int i = (bid - 2628) * 256 + tid;   // 16384, exact
        int m = i >> 7, k = i & 127;
        W2T[i] = bfc(Wm2[k * 128 + m]);
    } else if (bid < 2884) {                // Wf1 [384][128] -> T [128][384]
        int i = (bid - 2692) * 256 + tid;   // 49152, exact
        int c = i / 384, k = i - c * 384;
        Wf1T[i] = bfc(Wf1[k * 128 + c]);
    } else {                                // Wf2 [128][128] -> T
        int i = (bid - 2884) * 256 + tid;   // 16384, exact
        int c = i >> 7, k = i & 127;
        Wf2T[i] = bfc(Wf2[k * 128 + c]);
    }
}

// ---------- U|V kernel: [10000,128] x [128,256], 1 wave / 16 nodes ----------
// Both U (bias folded) and V written bf16.
__global__ __launch_bounds__(64) void uv_kernel(
    const float* __restrict__ feat,
    const short* __restrict__ WuvT,   // [256 c][128 k] bf16
    const float* __restrict__ bm1,
    short* __restrict__ Ub, short* __restrict__ Vb)
{
    const int l = threadIdx.x;
    const int l15 = l & 15, q = l >> 4;
    const int nbase = blockIdx.x * 16;            // grid 625, exact

    const float* p0 = feat + (size_t)(nbase + l15) * 128;

    floatx4 acc[16];
#pragma unroll
    for (int i = 0; i < 16; ++i) acc[i] = (floatx4)(0.f);

#pragma unroll
    for (int kk = 0; kk < 4; ++kk) {                    // K = 128
        const int krow = kk * 32 + q * 8;
        const float4 a0 = *(const float4*)(p0 + krow);
        const float4 a1 = *(const float4*)(p0 + krow + 4);
        short8 af;
        af[0] = bfc(a0.x); af[1] = bfc(a0.y); af[2] = bfc(a0.z); af[3] = bfc(a0.w);
        af[4] = bfc(a1.x); af[5] = bfc(a1.y); af[6] = bfc(a1.z); af[7] = bfc(a1.w);
#pragma unroll
        for (int ct = 0; ct < 16; ++ct) {
            const int c = ct * 16 + l15;
            short8 bf = *(const short8*)(WuvT + c * 128 + krow);
            acc[ct] = __builtin_amdgcn_mfma_f32_16x16x32_bf16(af, bf, acc[ct], 0, 0, 0);
        }
    }

#pragma unroll
    for (int ct = 0; ct < 8; ++ct) {
        const int c = ct * 16 + l15;
        const float b = bm1[c];
#pragma unroll
        for (int r = 0; r < 4; ++r)
            Ub[(size_t)(nbase + q * 4 + r) * 128 + c] = bfc(acc[ct][r] + b);
    }
#pragma unroll
    for (int ct = 8; ct < 16; ++ct) {
        const int c = ct * 16 + l15 - 128;
#pragma unroll
        for (int r = 0; r < 4; ++r)
            Vb[(size_t)(nbase + q * 4 + r) * 128 + c] = bfc(acc[ct][r]);
    }
}

// ---------- edge kernel: 4 waves/block, one node per wave ----------
// Walks the node's bin in 16-edge chunks:
//   h = sigmoid(U[n] + V[c_e]) (regs, both bf16) -> msg = h x W2 (MFMA, W2 L1)
//   -> softsign+mask -> register accumulate; one coalesced row store per node.
// __launch_bounds__(256,4): force <=128 total regs/wave -> 4 waves/SIMD.
__global__ __launch_bounds__(256, 4) void edge_kernel(
    const short* __restrict__ Ub,           // bf16 U (bias folded)
    const short* __restrict__ Vb,           // bf16 V
    const unsigned short* __restrict__ ecbin,
    const int* __restrict__ counts,
    const short* __restrict__ W2T,          // [128 m][128 k] bf16
    const float* __restrict__ bm2,
    float* __restrict__ agg)                // = d_out
{
    const int tid = threadIdx.x;
    const int w = tid >> 6, l = tid & 63;
    const int n = blockIdx.x * 4 + w;       // grid = 2500, exact
    const int q = l >> 4, l15 = l & 15;
    int cnt = counts[n];
    cnt = (cnt > BINW) ? BINW : cnt;
    const int start = n * BINW;

    if (cnt == 0) {                          // defensive; wave-uniform branch
        if (q == 0)
#pragma unroll
            for (int mt = 0; mt < 8; ++mt)
                agg[(size_t)n * 128 + mt * 16 + l15] = 0.f;
        return;
    }

    // per-lane U k-slices (bf16, 16 regs), constant across chunks
    const short* up = Ub + (size_t)n * 128 + q * 8;
    short8 uu[4];
#pragma unroll
    for (int kk2 = 0; kk2 < 4; ++kk2)
        uu[kk2] = *(const short8*)(up + kk2 * 32);

    float bmv[8];
#pragma unroll
    for (int mt = 0; mt < 8; ++mt) bmv[mt] = bm2[mt * 16 + l15];

    float sumreg[8];
#pragma unroll
    for (int mt = 0; mt < 8; ++mt) sumreg[mt] = 0.f;

    const int nch = (cnt + 15) >> 4;

    // 1-deep prefetch of edge cols
    int cnext = ecbin[start + ((l15 < cnt) ? l15 : cnt - 1)];

    for (int j = 0; j < nch; ++j) {
        const int c = cnext;
        const short* vp = Vb + (size_t)c * 128 + q * 8;

        // issue next chunk's ec load early
        if (j + 1 < nch) {
            int o = (j + 1) * 16 + l15;
            if (o >= cnt) o = cnt - 1;
            cnext = ecbin[start + o];
        }

        short8 hA[4];
#pragma unroll
        for (int kk2 = 0; kk2 < 4; ++kk2) {
            const short8 vv = *(const short8*)(vp + kk2 * 32);
            const short8 u8 = uu[kk2];
            short8 ha;
            ha[0] = bfc(sigmoidf_(bf2f(u8[0]) + bf2f(vv[0])));
            ha[1] = bfc(sigmoidf_(bf2f(u8[1]) + bf2f(vv[1])));
            ha[2] = bfc(sigmoidf_(bf2f(u8[2]) + bf2f(vv[2])));
            ha[3] = bfc(sigmoidf_(bf2f(u8[3]) + bf2f(vv[3])));
            ha[4] = bfc(sigmoidf_(bf2f(u8[4]) + bf2f(vv[4])));
            ha[5] = bfc(sigmoidf_(bf2f(u8[5]) + bf2f(vv[5])));
            ha[6] = bfc(sigmoidf_(bf2f(u8[6]) + bf2f(vv[6])));
            ha[7] = bfc(sigmoidf_(bf2f(u8[7]) + bf2f(vv[7])));
            hA[kk2] = ha;
        }

        floatx4 acc2[8];
#pragma unroll
        for (int i = 0; i < 8; ++i) acc2[i] = (floatx4)(0.f);
#pragma unroll
        for (int kk2 = 0; kk2 < 4; ++kk2) {
#pragma unroll
            for (int mt = 0; mt < 8; ++mt) {
                short8 wfr = *(const short8*)(W2T + (mt * 16 + l15) * 128
                                              + kk2 * 32 + q * 8);
                acc2[mt] = __builtin_amdgcn_mfma_f32_16x16x32_bf16(
                    hA[kk2], wfr, acc2[mt], 0, 0, 0);
            }
        }

        const int eb = j * 16 + q * 4;      // acc2[mt][r] = msg[edge eb+r][m]
#pragma unroll
        for (int mt = 0; mt < 8; ++mt) {
            float s = 0.f;
#pragma unroll
            for (int r = 0; r < 4; ++r)
                if (eb + r < cnt) s += softsignf_(acc2[mt][r] + bmv[mt]);
            sumreg[mt] += s;
        }
    }

#pragma unroll
    for (int mt = 0; mt < 8; ++mt) {
        float s = sumreg[mt];
        s += __shfl_xor(s, 16);
        s += __shfl_xor(s, 32);
        if (q == 0) agg[(size_t)n * 128 + mt * 16 + l15] = s;
    }
}

// ---------- node kernel: 1 wave / 16 nodes ----------
// NOTE: agg aliases out (d_out). Node n reads agg row n strictly before
// writing out row n; waves own disjoint node ranges.
__global__ __launch_bounds__(64) void node_kernel(
    const float* __restrict__ feat,
    const float* agg,
    const float* __restrict__ temb,
    const short* __restrict__ Wf1T,
    const float* __restrict__ bf1v,
    const short* __restrict__ Wf2T,
    const float* __restrict__ bf2v,
    float* out)
{
    __shared__ __align__(16) short gbuf[16][128];
    const int l = threadIdx.x;
    const int l15 = l & 15, q = l >> 4;
    const int nbase = blockIdx.x * 16;            // grid 625, exact

    const int nA = nbase + l15;
    const float* p0 = feat + (size_t)nA * 128 + q * 8;
    const float* p1 = agg + (size_t)nA * 128 + q * 8;
    const float* p2 = temb + (size_t)nA * 128 + q * 8;

    floatx4 acc[8];
#pragma unroll
    for (int i = 0; i < 8; ++i) acc[i] = (floatx4)(0.f);

#pragma unroll
    for (int kk = 0; kk < 12; ++kk) {                   // K = 384 = 12 x 32
        const float* ap = (kk < 4) ? (p0 + kk * 32)
                        : (kk < 8) ? (p1 + (kk - 4) * 32)
                                   : (p2 + (kk - 8) * 32);
        const float4 a0 = *(const float4*)(ap);
        const float4 a1 = *(const float4*)(ap + 4);
        short8 af;
        af[0] = bfc(sigmoidf_(a0.x)); af[1] = bfc(sigmoidf_(a0.y));
        af[2] = bfc(sigmoidf_(a0.z)); af[3] = bfc(sigmoidf_(a0.w));
        af[4] = bfc(sigmoidf_(a1.x)); af[5] = bfc(sigmoidf_(a1.y));
        af[6] = bfc(sigmoidf_(a1.z)); af[7] = bfc(sigmoidf_(a1.w));
        const int krow = kk * 32 + q * 8;
#pragma unroll
        for (int ct = 0; ct < 8; ++ct) {
            const int col = ct * 16 + l15;
            short8 bf = *(const short8*)(Wf1T + col * 384 + krow);
            acc[ct] = __builtin_amdgcn_mfma_f32_16x16x32_bf16(af, bf, acc[ct], 0, 0, 0);
        }
    }

#pragma unroll
    for (int ct = 0; ct < 8; ++ct) {
        const int col = ct * 16 + l15;
        const float b = bf1v[col];
#pragma unroll
        for (int r = 0; r < 4; ++r) {
            gbuf[q * 4 + r][col] = bfc(sigmoidf_(acc[ct][r] + b));
        }
    }

    floatx4 acc2[8];
#pragma unroll
    for (int i = 0; i < 8; ++i) acc2[i] = (floatx4)(0.f);
#pragma unroll
    for (int kk = 0; kk < 4; ++kk) {
        const int krow = kk * 32 + q * 8;
        short8 af = *(const short8*)(&gbuf[l15][krow]);
#pragma unroll
        for (int ct = 0; ct < 8; ++ct) {
            const int col = ct * 16 + l15;
            short8 bf = *(const short8*)(Wf2T + col * 128 + krow);
            acc2[ct] = __builtin_amdgcn_mfma_f32_16x16x32_bf16(af, bf, acc2[ct], 0, 0, 0);
        }
    }

#pragma unroll
    for (int ct = 0; ct < 8; ++ct) {
        const int col = ct * 16 + l15;
        const float b = bf2v[col];
#pragma unroll
        for (int r = 0; r < 4; ++r) {
            const int node = nbase + q * 4 + r;
            out[(size_t)node * 128 + col] = softsignf_(acc2[ct][r] + b);
        }
    }
}

extern "C" void kernel_launch(void* const* d_in, const int* in_sizes, int n_in,
                              void* d_out, int out_size, void* d_ws, size_t ws_size,
                              hipStream_t stream)
{
    const float* feat = (const float*)d_in[0];
    const int* rows = (const int*)d_in[1];
    const int* cols = (const int*)d_in[2];
    const float* temb = (const float*)d_in[3];
    const float* Wm1 = (const float*)d_in[4];
    const float* bm1 = (const float*)d_in[5];
    const float* Wm2 = (const float*)d_in[6];
    const float* bm2 = (const float*)d_in[7];
    const float* Wf1 = (const float*)d_in[8];
    const float* bf1 = (const float*)d_in[9];
    const float* Wf2 = (const float*)d_in[10];
    const float* bf2 = (const float*)d_in[11];
    float* out = (float*)d_out;
    float* agg = (float*)d_out;   // aliased: edge stores rows here, node reads row n before writing it

    // Workspace layout (16B-aligned):
    //   Ub     bf16 [10000][128]      2,560,000 B   @ 0
    //   Vb     bf16 [10000][128]      2,560,000 B   @ 2,560,000
    //   WuvT   bf16 [256][128]           65,536 B   @ 5,120,000
    //   W2T    bf16 [128][128]           32,768 B   @ 5,185,536
    //   Wf1T   bf16 [128][384]           98,304 B   @ 5,218,304
    //   Wf2T   bf16 [128][128]           32,768 B   @ 5,316,608
    //   ecbin  u16  [10000][160]      3,200,000 B   @ 5,349,376
    //   counts i32  [NN]                 40,000 B   @ 8,549,376
    char* ws = (char*)d_ws;
    short* Ub    = (short*)ws;
    short* Vb    = (short*)(ws + 2560000);
    short* WuvT  = (short*)(ws + 5120000);
    short* W2T   = (short*)(ws + 5185536);
    short* Wf1T  = (short*)(ws + 5218304);
    short* Wf2T  = (short*)(ws + 5316608);
    unsigned short* ecbin = (unsigned short*)(ws + 5349376);
    int* counts  = (int*)(ws + 8549376);

    hipMemsetAsync(counts, 0, NN * sizeof(int), stream);
    prep_all<<<2948, 256, 0, stream>>>(rows, cols, Wm1, Wm2, Wf1, Wf2,
                                       WuvT, W2T, Wf1T, Wf2T, counts, ecbin);
    uv_kernel<<<625, 64, 0, stream>>>(feat, WuvT, bm1, Ub, Vb);

    edge_kernel<<<NN / 4, 256, 0, stream>>>(Ub, Vb, ecbin, counts, W2T, bm2, agg);
    node_kernel<<<625, 64, 0, stream>>>(feat, agg, temb, Wf1T, bf1, Wf2T, bf2, out);
}

// Round 17
// 171.321 us; speedup vs baseline: 2.0983x; 2.0983x over previous
//
#include <hip/hip_runtime.h>
#include <hip/hip_bf16.h>

// Graph message-passing layer, bf16 MFMA implementation, v17.
// = v14 dataflow (verified 172us) + Ub stored bf16 (u-state 32->16 regs,
// numerics verified in v16: absmax unchanged). NO launch_bounds forcing —
// v16's (256,4) made the allocator squeeze to 64 arch VGPRs and spill
// (FETCH 14->681 MB, edge 94->286us). Target: VGPR ~112 (< the 128
// occupancy-halving boundary) with compiler-chosen allocation.
// N=10000, E=640000, F=M=O=128.

#define NN 10000
#define NE 640000
#define BINW 160

typedef __attribute__((ext_vector_type(8))) short short8;
typedef __attribute__((ext_vector_type(4))) short short4v;
typedef __attribute__((ext_vector_type(4))) float floatx4;

__device__ __forceinline__ short bfc(float f) {
    __hip_bfloat16 h = __float2bfloat16(f);
    return *reinterpret_cast<short*>(&h);
}
__device__ __forceinline__ float bf2f(short s) {
    union { unsigned u; float f; } v; v.u = ((unsigned)(unsigned short)s) << 16;
    return v.f;
}

__device__ __forceinline__ float sigmoidf_(float x) {
    return __builtin_amdgcn_rcpf(1.f + __expf(-x));
}
__device__ __forceinline__ float softsignf_(float x) {
    return x * __builtin_amdgcn_rcpf(1.f + fabsf(x));
}

// ---------- fused prep kernel ----------
// partitions: [0,2500) edge binning | [2500,2628) WuvT | [2628,2692) W2T
// | [2692,2884) Wf1T | [2884,2948) Wf2T
__global__ __launch_bounds__(256) void prep_all(
    const int* __restrict__ rows, const int* __restrict__ cols,
    const float* __restrict__ Wm1, const float* __restrict__ Wm2,
    const float* __restrict__ Wf1, const float* __restrict__ Wf2,
    short* __restrict__ WuvT, short* __restrict__ W2T,
    short* __restrict__ Wf1T, short* __restrict__ Wf2T,
    int* __restrict__ counts, unsigned short* __restrict__ ecbin)
{
    const int bid = blockIdx.x, tid = threadIdx.x;
    if (bid < 2500) {                       // bin edges by source node (640000, exact)
        int e = bid * 256 + tid;
        int r = rows[e];
        int p = atomicAdd(&counts[r], 1);
        if (p < BINW) ecbin[r * BINW + p] = (unsigned short)cols[e];
    } else if (bid < 2628) {                // WuvT[256][128]: c<128 -> W1a^T else W1b^T
        int i = (bid - 2500) * 256 + tid;   // 32768, exact
        int c = i >> 7, k = i & 127;
        WuvT[i] = bfc(Wm1[(k + ((c >> 7) << 7)) * 128 + (c & 127)]);
    } else if (bid < 2692) {                // Wm2 [128][128] -> plain T [m][k]
        int i = (bid - 2628) * 256 + tid;   // 16384, exact
        int m = i >> 7, k = i & 127;
        W2T[i] = bfc(Wm2[k * 128 + m]);
    } else if (bid < 2884) {                // Wf1 [384][128] -> T [128][384]
        int i = (bid - 2692) * 256 + tid;   // 49152, exact
        int c = i / 384, k = i - c * 384;
        Wf1T[i] = bfc(Wf1[k * 128 + c]);
    } else {                                // Wf2 [128][128] -> T
        int i = (bid - 2884) * 256 + tid;   // 16384, exact
        int c = i >> 7, k = i & 127;
        Wf2T[i] = bfc(Wf2[k * 128 + c]);
    }
}

// ---------- U|V kernel: [10000,128] x [128,256], 1 wave / 16 nodes ----------
// Both U (bias folded) and V written bf16.
__global__ __launch_bounds__(64) void uv_kernel(
    const float* __restrict__ feat,
    const short* __restrict__ WuvT,   // [256 c][128 k] bf16
    const float* __restrict__ bm1,
    short* __restrict__ Ub, short* __restrict__ Vb)
{
    const int l = threadIdx.x;
    const int l15 = l & 15, q = l >> 4;
    const int nbase = blockIdx.x * 16;            // grid 625, exact

    const float* p0 = feat + (size_t)(nbase + l15) * 128;

    floatx4 acc[16];
#pragma unroll
    for (int i = 0; i < 16; ++i) acc[i] = (floatx4)(0.f);

#pragma unroll
    for (int kk = 0; kk < 4; ++kk) {                    // K = 128
        const int krow = kk * 32 + q * 8;
        const float4 a0 = *(const float4*)(p0 + krow);
        const float4 a1 = *(const float4*)(p0 + krow + 4);
        short8 af;
        af[0] = bfc(a0.x); af[1] = bfc(a0.y); af[2] = bfc(a0.z); af[3] = bfc(a0.w);
        af[4] = bfc(a1.x); af[5] = bfc(a1.y); af[6] = bfc(a1.z); af[7] = bfc(a1.w);
#pragma unroll
        for (int ct = 0; ct < 16; ++ct) {
            const int c = ct * 16 + l15;
            short8 bf = *(const short8*)(WuvT + c * 128 + krow);
            acc[ct] = __builtin_amdgcn_mfma_f32_16x16x32_bf16(af, bf, acc[ct], 0, 0, 0);
        }
    }

#pragma unroll
    for (int ct = 0; ct < 8; ++ct) {
        const int c = ct * 16 + l15;
        const float b = bm1[c];
#pragma unroll
        for (int r = 0; r < 4; ++r)
            Ub[(size_t)(nbase + q * 4 + r) * 128 + c] = bfc(acc[ct][r] + b);
    }
#pragma unroll
    for (int ct = 8; ct < 16; ++ct) {
        const int c = ct * 16 + l15 - 128;
#pragma unroll
        for (int r = 0; r < 4; ++r)
            Vb[(size_t)(nbase + q * 4 + r) * 128 + c] = bfc(acc[ct][r]);
    }
}

// ---------- edge kernel: 4 waves/block, one node per wave ----------
// Walks the node's bin in 16-edge chunks:
//   h = sigmoid(U[n] + V[c_e]) (regs, both bf16) -> msg = h x W2 (MFMA, W2 L1)
//   -> softsign+mask -> register accumulate; one coalesced row store per node.
__global__ __launch_bounds__(256) void edge_kernel(
    const short* __restrict__ Ub,           // bf16 U (bias folded)
    const short* __restrict__ Vb,           // bf16 V
    const unsigned short* __restrict__ ecbin,
    const int* __restrict__ counts,
    const short* __restrict__ W2T,          // [128 m][128 k] bf16
    const float* __restrict__ bm2,
    float* __restrict__ agg)                // = d_out
{
    const int tid = threadIdx.x;
    const int w = tid >> 6, l = tid & 63;
    const int n = blockIdx.x * 4 + w;       // grid = 2500, exact
    const int q = l >> 4, l15 = l & 15;
    int cnt = counts[n];
    cnt = (cnt > BINW) ? BINW : cnt;
    const int start = n * BINW;

    if (cnt == 0) {                          // defensive; wave-uniform branch
        if (q == 0)
#pragma unroll
            for (int mt = 0; mt < 8; ++mt)
                agg[(size_t)n * 128 + mt * 16 + l15] = 0.f;
        return;
    }

    // per-lane U k-slices (bf16, 16 regs), constant across chunks
    const short* up = Ub + (size_t)n * 128 + q * 8;
    short8 uu[4];
#pragma unroll
    for (int kk2 = 0; kk2 < 4; ++kk2)
        uu[kk2] = *(const short8*)(up + kk2 * 32);

    float bmv[8];
#pragma unroll
    for (int mt = 0; mt < 8; ++mt) bmv[mt] = bm2[mt * 16 + l15];

    float sumreg[8];
#pragma unroll
    for (int mt = 0; mt < 8; ++mt) sumreg[mt] = 0.f;

    const int nch = (cnt + 15) >> 4;

    // 1-deep prefetch of edge cols
    int cnext = ecbin[start + ((l15 < cnt) ? l15 : cnt - 1)];

    for (int j = 0; j < nch; ++j) {
        const int c = cnext;
        const short* vp = Vb + (size_t)c * 128 + q * 8;

        // issue next chunk's ec load early
        if (j + 1 < nch) {
            int o = (j + 1) * 16 + l15;
            if (o >= cnt) o = cnt - 1;
            cnext = ecbin[start + o];
        }

        short8 hA[4];
#pragma unroll
        for (int kk2 = 0; kk2 < 4; ++kk2) {
            const short8 vv = *(const short8*)(vp + kk2 * 32);
            const short8 u8 = uu[kk2];
            short8 ha;
            ha[0] = bfc(sigmoidf_(bf2f(u8[0]) + bf2f(vv[0])));
            ha[1] = bfc(sigmoidf_(bf2f(u8[1]) + bf2f(vv[1])));
            ha[2] = bfc(sigmoidf_(bf2f(u8[2]) + bf2f(vv[2])));
            ha[3] = bfc(sigmoidf_(bf2f(u8[3]) + bf2f(vv[3])));
            ha[4] = bfc(sigmoidf_(bf2f(u8[4]) + bf2f(vv[4])));
            ha[5] = bfc(sigmoidf_(bf2f(u8[5]) + bf2f(vv[5])));
            ha[6] = bfc(sigmoidf_(bf2f(u8[6]) + bf2f(vv[6])));
            ha[7] = bfc(sigmoidf_(bf2f(u8[7]) + bf2f(vv[7])));
            hA[kk2] = ha;
        }

        floatx4 acc2[8];
#pragma unroll
        for (int i = 0; i < 8; ++i) acc2[i] = (floatx4)(0.f);
#pragma unroll
        for (int kk2 = 0; kk2 < 4; ++kk2) {
#pragma unroll
            for (int mt = 0; mt < 8; ++mt) {
                short8 wfr = *(const short8*)(W2T + (mt * 16 + l15) * 128
                                              + kk2 * 32 + q * 8);
                acc2[mt] = __builtin_amdgcn_mfma_f32_16x16x32_bf16(
                    hA[kk2], wfr, acc2[mt], 0, 0, 0);
            }
        }

        const int eb = j * 16 + q * 4;      // acc2[mt][r] = msg[edge eb+r][m]
#pragma unroll
        for (int mt = 0; mt < 8; ++mt) {
            float s = 0.f;
#pragma unroll
            for (int r = 0; r < 4; ++r)
                if (eb + r < cnt) s += softsignf_(acc2[mt][r] + bmv[mt]);
            sumreg[mt] += s;
        }
    }

#pragma unroll
    for (int mt = 0; mt < 8; ++mt) {
        float s = sumreg[mt];
        s += __shfl_xor(s, 16);
        s += __shfl_xor(s, 32);
        if (q == 0) agg[(size_t)n * 128 + mt * 16 + l15] = s;
    }
}

// ---------- node kernel: 1 wave / 16 nodes ----------
// NOTE: agg aliases out (d_out). Node n reads agg row n strictly before
// writing out row n; waves own disjoint node ranges.
__global__ __launch_bounds__(64) void node_kernel(
    const float* __restrict__ feat,
    const float* agg,
    const float* __restrict__ temb,
    const short* __restrict__ Wf1T,
    const float* __restrict__ bf1v,
    const short* __restrict__ Wf2T,
    const float* __restrict__ bf2v,
    float* out)
{
    __shared__ __align__(16) short gbuf[16][128];
    const int l = threadIdx.x;
    const int l15 = l & 15, q = l >> 4;
    const int nbase = blockIdx.x * 16;            // grid 625, exact

    const int nA = nbase + l15;
    const float* p0 = feat + (size_t)nA * 128 + q * 8;
    const float* p1 = agg + (size_t)nA * 128 + q * 8;
    const float* p2 = temb + (size_t)nA * 128 + q * 8;

    floatx4 acc[8];
#pragma unroll
    for (int i = 0; i < 8; ++i) acc[i] = (floatx4)(0.f);

#pragma unroll
    for (int kk = 0; kk < 12; ++kk) {                   // K = 384 = 12 x 32
        const float* ap = (kk < 4) ? (p0 + kk * 32)
                        : (kk < 8) ? (p1 + (kk - 4) * 32)
                                   : (p2 + (kk - 8) * 32);
        const float4 a0 = *(const float4*)(ap);
        const float4 a1 = *(const float4*)(ap + 4);
        short8 af;
        af[0] = bfc(sigmoidf_(a0.x)); af[1] = bfc(sigmoidf_(a0.y));
        af[2] = bfc(sigmoidf_(a0.z)); af[3] = bfc(sigmoidf_(a0.w));
        af[4] = bfc(sigmoidf_(a1.x)); af[5] = bfc(sigmoidf_(a1.y));
        af[6] = bfc(sigmoidf_(a1.z)); af[7] = bfc(sigmoidf_(a1.w));
        const int krow = kk * 32 + q * 8;
#pragma unroll
        for (int ct = 0; ct < 8; ++ct) {
            const int col = ct * 16 + l15;
            short8 bf = *(const short8*)(Wf1T + col * 384 + krow);
            acc[ct] = __builtin_amdgcn_mfma_f32_16x16x32_bf16(af, bf, acc[ct], 0, 0, 0);
        }
    }

#pragma unroll
    for (int ct = 0; ct < 8; ++ct) {
        const int col = ct * 16 + l15;
        const float b = bf1v[col];
#pragma unroll
        for (int r = 0; r < 4; ++r) {
            gbuf[q * 4 + r][col] = bfc(sigmoidf_(acc[ct][r] + b));
        }
    }

    floatx4 acc2[8];
#pragma unroll
    for (int i = 0; i < 8; ++i) acc2[i] = (floatx4)(0.f);
#pragma unroll
    for (int kk = 0; kk < 4; ++kk) {
        const int krow = kk * 32 + q * 8;
        short8 af = *(const short8*)(&gbuf[l15][krow]);
#pragma unroll
        for (int ct = 0; ct < 8; ++ct) {
            const int col = ct * 16 + l15;
            short8 bf = *(const short8*)(Wf2T + col * 128 + krow);
            acc2[ct] = __builtin_amdgcn_mfma_f32_16x16x32_bf16(af, bf, acc2[ct], 0, 0, 0);
        }
    }

#pragma unroll
    for (int ct = 0; ct < 8; ++ct) {
        const int col = ct * 16 + l15;
        const float b = bf2v[col];
#pragma unroll
        for (int r = 0; r < 4; ++r) {
            const int node = nbase + q * 4 + r;
            out[(size_t)node * 128 + col] = softsignf_(acc2[ct][r] + b);
        }
    }
}

extern "C" void kernel_launch(void* const* d_in, const int* in_sizes, int n_in,
                              void* d_out, int out_size, void* d_ws, size_t ws_size,
                              hipStream_t stream)
{
    const float* feat = (const float*)d_in[0];
    const int* rows = (const int*)d_in[1];
    const int* cols = (const int*)d_in[2];
    const float* temb = (const float*)d_in[3];
    const float* Wm1 = (const float*)d_in[4];
    const float* bm1 = (const float*)d_in[5];
    const float* Wm2 = (const float*)d_in[6];
    const float* bm2 = (const float*)d_in[7];
    const float* Wf1 = (const float*)d_in[8];
    const float* bf1 = (const float*)d_in[9];
    const float* Wf2 = (const float*)d_in[10];
    const float* bf2 = (const float*)d_in[11];
    float* out = (float*)d_out;
    float* agg = (float*)d_out;   // aliased: edge stores rows here, node reads row n before writing it

    // Workspace layout (16B-aligned):
    //   Ub     bf16 [10000][128]      2,560,000 B   @ 0
    //   Vb     bf16 [10000][128]      2,560,000 B   @ 2,560,000
    //   WuvT   bf16 [256][128]           65,536 B   @ 5,120,000
    //   W2T    bf16 [128][128]           32,768 B   @ 5,185,536
    //   Wf1T   bf16 [128][384]           98,304 B   @ 5,218,304
    //   Wf2T   bf16 [128][128]           32,768 B   @ 5,316,608
    //   ecbin  u16  [10000][160]      3,200,000 B   @ 5,349,376
    //   counts i32  [NN]                 40,000 B   @ 8,549,376
    char* ws = (char*)d_ws;
    short* Ub    = (short*)ws;
    short* Vb    = (short*)(ws + 2560000);
    short* WuvT  = (short*)(ws + 5120000);
    short* W2T   = (short*)(ws + 5185536);
    short* Wf1T  = (short*)(ws + 5218304);
    short* Wf2T  = (short*)(ws + 5316608);
    unsigned short* ecbin = (unsigned short*)(ws + 5349376);
    int* counts  = (int*)(ws + 8549376);

    hipMemsetAsync(counts, 0, NN * sizeof(int), stream);
    prep_all<<<2948, 256, 0, stream>>>(rows, cols, Wm1, Wm2, Wf1, Wf2,
                                       WuvT, W2T, Wf1T, Wf2T, counts, ecbin);
    uv_kernel<<<625, 64, 0, stream>>>(feat, WuvT, bm1, Ub, Vb);

    edge_kernel<<<NN / 4, 256, 0, stream>>>(Ub, Vb, ecbin, counts, W2T, bm2, agg);
    node_kernel<<<625, 64, 0, stream>>>(feat, agg, temb, Wf1T, bf1, Wf2T, bf2, out);
}

// Round 19
// 146.160 us; speedup vs baseline: 2.4595x; 1.1721x over previous
//
#include <hip/hip_runtime.h>
#include <hip/hip_bf16.h>

// Graph message-passing layer, bf16 MFMA implementation, v19.
// = v18 with the W2 LDS staging bug fixed: v18 copied only 512 of 2048
// short8 slots (pattern from the 1024-thread v11 kernel used in a 256-thread
// block) -> 3/4 of LDS was undefined -> NaN. Now each of 256 threads stages
// 8 short8s. Everything else identical to v18 (W2 in swizzled LDS to break
// the compiler's loop-invariant W2-hoist that pinned VGPR at 128).
// N=10000, E=640000, F=M=O=128.

#define NN 10000
#define NE 640000
#define BINW 160

typedef __attribute__((ext_vector_type(8))) short short8;
typedef __attribute__((ext_vector_type(4))) short short4v;
typedef __attribute__((ext_vector_type(4))) float floatx4;

__device__ __forceinline__ short bfc(float f) {
    __hip_bfloat16 h = __float2bfloat16(f);
    return *reinterpret_cast<short*>(&h);
}
__device__ __forceinline__ float bf2f(short s) {
    union { unsigned u; float f; } v; v.u = ((unsigned)(unsigned short)s) << 16;
    return v.f;
}

__device__ __forceinline__ float sigmoidf_(float x) {
    return __builtin_amdgcn_rcpf(1.f + __expf(-x));
}
__device__ __forceinline__ float softsignf_(float x) {
    return x * __builtin_amdgcn_rcpf(1.f + fabsf(x));
}

// ---------- fused prep kernel ----------
// partitions: [0,2500) edge binning | [2500,2628) WuvT | [2628,2692) W2 swz
// | [2692,2884) Wf1T | [2884,2948) Wf2T
__global__ __launch_bounds__(256) void prep_all(
    const int* __restrict__ rows, const int* __restrict__ cols,
    const float* __restrict__ Wm1, const float* __restrict__ Wm2,
    const float* __restrict__ Wf1, const float* __restrict__ Wf2,
    short* __restrict__ WuvT, short* __restrict__ W2s,
    short* __restrict__ Wf1T, short* __restrict__ Wf2T,
    int* __restrict__ counts, unsigned short* __restrict__ ecbin)
{
    const int bid = blockIdx.x, tid = threadIdx.x;
    if (bid < 2500) {                       // bin edges by source node (640000, exact)
        int e = bid * 256 + tid;
        int r = rows[e];
        int p = atomicAdd(&counts[r], 1);
        if (p < BINW) ecbin[r * BINW + p] = (unsigned short)cols[e];
    } else if (bid < 2628) {                // WuvT[256][128]: c<128 -> W1a^T else W1b^T
        int i = (bid - 2500) * 256 + tid;   // 32768, exact
        int c = i >> 7, k = i & 127;
        WuvT[i] = bfc(Wm1[(k + ((c >> 7) << 7)) * 128 + (c & 127)]);
    } else if (bid < 2692) {                // Wm2 [128][128] -> swz T [m][k^((m&7)<<3)]
        int i = (bid - 2628) * 256 + tid;   // 16384, exact
        int m = i >> 7, k = i & 127;
        W2s[m * 128 + (k ^ ((m & 7) << 3))] = bfc(Wm2[k * 128 + m]);
    } else if (bid < 2884) {                // Wf1 [384][128] -> T [128][384]
        int i = (bid - 2692) * 256 + tid;   // 49152, exact
        int c = i / 384, k = i - c * 384;
        Wf1T[i] = bfc(Wf1[k * 128 + c]);
    } else {                                // Wf2 [128][128] -> T
        int i = (bid - 2884) * 256 + tid;   // 16384, exact
        int c = i >> 7, k = i & 127;
        Wf2T[i] = bfc(Wf2[k * 128 + c]);
    }
}

// ---------- U|V kernel: [10000,128] x [128,256], 1 wave / 16 nodes ----------
// Both U (bias folded) and V written bf16.
__global__ __launch_bounds__(64) void uv_kernel(
    const float* __restrict__ feat,
    const short* __restrict__ WuvT,   // [256 c][128 k] bf16
    const float* __restrict__ bm1,
    short* __restrict__ Ub, short* __restrict__ Vb)
{
    const int l = threadIdx.x;
    const int l15 = l & 15, q = l >> 4;
    const int nbase = blockIdx.x * 16;            // grid 625, exact

    const float* p0 = feat + (size_t)(nbase + l15) * 128;

    floatx4 acc[16];
#pragma unroll
    for (int i = 0; i < 16; ++i) acc[i] = (floatx4)(0.f);

#pragma unroll
    for (int kk = 0; kk < 4; ++kk) {                    // K = 128
        const int krow = kk * 32 + q * 8;
        const float4 a0 = *(const float4*)(p0 + krow);
        const float4 a1 = *(const float4*)(p0 + krow + 4);
        short8 af;
        af[0] = bfc(a0.x); af[1] = bfc(a0.y); af[2] = bfc(a0.z); af[3] = bfc(a0.w);
        af[4] = bfc(a1.x); af[5] = bfc(a1.y); af[6] = bfc(a1.z); af[7] = bfc(a1.w);
#pragma unroll
        for (int ct = 0; ct < 16; ++ct) {
            const int c = ct * 16 + l15;
            short8 bf = *(const short8*)(WuvT + c * 128 + krow);
            acc[ct] = __builtin_amdgcn_mfma_f32_16x16x32_bf16(af, bf, acc[ct], 0, 0, 0);
        }
    }

#pragma unroll
    for (int ct = 0; ct < 8; ++ct) {
        const int c = ct * 16 + l15;
        const float b = bm1[c];
#pragma unroll
        for (int r = 0; r < 4; ++r)
            Ub[(size_t)(nbase + q * 4 + r) * 128 + c] = bfc(acc[ct][r] + b);
    }
#pragma unroll
    for (int ct = 8; ct < 16; ++ct) {
        const int c = ct * 16 + l15 - 128;
#pragma unroll
        for (int r = 0; r < 4; ++r)
            Vb[(size_t)(nbase + q * 4 + r) * 128 + c] = bfc(acc[ct][r]);
    }
}

// ---------- edge kernel: 4 waves/block, one node per wave ----------
// Walks the node's bin in 16-edge chunks:
//   h = sigmoid(U[n] + V[c_e]) (regs, both bf16) -> msg = h x W2 (MFMA,
//   W2 in swizzled LDS) -> softsign+mask -> register accumulate;
//   one coalesced row store per node.
__global__ __launch_bounds__(256) void edge_kernel(
    const short* __restrict__ Ub,           // bf16 U (bias folded)
    const short* __restrict__ Vb,           // bf16 V
    const unsigned short* __restrict__ ecbin,
    const int* __restrict__ counts,
    const short* __restrict__ W2s,          // swizzled [128][128]
    const float* __restrict__ bm2,
    float* __restrict__ agg)                // = d_out
{
    __shared__ __align__(16) short wlds[16384];   // 32 KB: W2 swizzled
    const int tid = threadIdx.x;
    const int w = tid >> 6, l = tid & 63;
    const int n = blockIdx.x * 4 + w;       // grid = 2500, exact
    const int q = l >> 4, l15 = l & 15;

    // stage W2: 2048 short8 slots, 256 threads x 8 each (full coverage)
    {
        const short8* gs = (const short8*)W2s;
        short8* ls = (short8*)wlds;
#pragma unroll
        for (int i = 0; i < 8; ++i) ls[i * 256 + tid] = gs[i * 256 + tid];
    }

    int cnt = counts[n];
    cnt = (cnt > BINW) ? BINW : cnt;
    const int start = n * BINW;

    // per-lane U k-slices (bf16, 16 regs), constant across chunks
    const short* up = Ub + (size_t)n * 128 + q * 8;
    short8 uu[4];
#pragma unroll
    for (int kk2 = 0; kk2 < 4; ++kk2)
        uu[kk2] = *(const short8*)(up + kk2 * 32);

    float bmv[8];
#pragma unroll
    for (int mt = 0; mt < 8; ++mt) bmv[mt] = bm2[mt * 16 + l15];

    float sumreg[8];
#pragma unroll
    for (int mt = 0; mt < 8; ++mt) sumreg[mt] = 0.f;

    __syncthreads();

    if (cnt > 0) {
        const int nch = (cnt + 15) >> 4;

        // 1-deep prefetch of edge cols
        int cnext = ecbin[start + ((l15 < cnt) ? l15 : cnt - 1)];

        for (int j = 0; j < nch; ++j) {
            const int c = cnext;
            const short* vp = Vb + (size_t)c * 128 + q * 8;

            // issue next chunk's ec load early
            if (j + 1 < nch) {
                int o = (j + 1) * 16 + l15;
                if (o >= cnt) o = cnt - 1;
                cnext = ecbin[start + o];
            }

            short8 hA[4];
#pragma unroll
            for (int kk2 = 0; kk2 < 4; ++kk2) {
                const short8 vv = *(const short8*)(vp + kk2 * 32);
                const short8 u8 = uu[kk2];
                short8 ha;
                ha[0] = bfc(sigmoidf_(bf2f(u8[0]) + bf2f(vv[0])));
                ha[1] = bfc(sigmoidf_(bf2f(u8[1]) + bf2f(vv[1])));
                ha[2] = bfc(sigmoidf_(bf2f(u8[2]) + bf2f(vv[2])));
                ha[3] = bfc(sigmoidf_(bf2f(u8[3]) + bf2f(vv[3])));
                ha[4] = bfc(sigmoidf_(bf2f(u8[4]) + bf2f(vv[4])));
                ha[5] = bfc(sigmoidf_(bf2f(u8[5]) + bf2f(vv[5])));
                ha[6] = bfc(sigmoidf_(bf2f(u8[6]) + bf2f(vv[6])));
                ha[7] = bfc(sigmoidf_(bf2f(u8[7]) + bf2f(vv[7])));
                hA[kk2] = ha;
            }

            floatx4 acc2[8];
#pragma unroll
            for (int i = 0; i < 8; ++i) acc2[i] = (floatx4)(0.f);
#pragma unroll
            for (int kk2 = 0; kk2 < 4; ++kk2) {
#pragma unroll
                for (int mt = 0; mt < 8; ++mt) {
                    const int m = mt * 16 + l15;
                    const int idx = m * 128 + ((kk2 * 32 + q * 8) ^ ((m & 7) << 3));
                    short8 wfr = *(const short8*)(wlds + idx);
                    acc2[mt] = __builtin_amdgcn_mfma_f32_16x16x32_bf16(
                        hA[kk2], wfr, acc2[mt], 0, 0, 0);
                }
            }

            const int eb = j * 16 + q * 4;  // acc2[mt][r] = msg[edge eb+r][m]
#pragma unroll
            for (int mt = 0; mt < 8; ++mt) {
                float s = 0.f;
#pragma unroll
                for (int r = 0; r < 4; ++r)
                    if (eb + r < cnt) s += softsignf_(acc2[mt][r] + bmv[mt]);
                sumreg[mt] += s;
            }
        }
    }

#pragma unroll
    for (int mt = 0; mt < 8; ++mt) {
        float s = sumreg[mt];
        s += __shfl_xor(s, 16);
        s += __shfl_xor(s, 32);
        if (q == 0) agg[(size_t)n * 128 + mt * 16 + l15] = s;
    }
}

// ---------- node kernel: 1 wave / 16 nodes ----------
// NOTE: agg aliases out (d_out). Node n reads agg row n strictly before
// writing out row n; waves own disjoint node ranges.
__global__ __launch_bounds__(64) void node_kernel(
    const float* __restrict__ feat,
    const float* agg,
    const float* __restrict__ temb,
    const short* __restrict__ Wf1T,
    const float* __restrict__ bf1v,
    const short* __restrict__ Wf2T,
    const float* __restrict__ bf2v,
    float* out)
{
    __shared__ __align__(16) short gbuf[16][128];
    const int l = threadIdx.x;
    const int l15 = l & 15, q = l >> 4;
    const int nbase = blockIdx.x * 16;            // grid 625, exact

    const int nA = nbase + l15;
    const float* p0 = feat + (size_t)nA * 128 + q * 8;
    const float* p1 = agg + (size_t)nA * 128 + q * 8;
    const float* p2 = temb + (size_t)nA * 128 + q * 8;

    floatx4 acc[8];
#pragma unroll
    for (int i = 0; i < 8; ++i) acc[i] = (floatx4)(0.f);

#pragma unroll
    for (int kk = 0; kk < 12; ++kk) {                   // K = 384 = 12 x 32
        const float* ap = (kk < 4) ? (p0 + kk * 32)
                        : (kk < 8) ? (p1 + (kk - 4) * 32)
                                   : (p2 + (kk - 8) * 32);
        const float4 a0 = *(const float4*)(ap);
        const float4 a1 = *(const float4*)(ap + 4);
        short8 af;
        af[0] = bfc(sigmoidf_(a0.x)); af[1] = bfc(sigmoidf_(a0.y));
        af[2] = bfc(sigmoidf_(a0.z)); af[3] = bfc(sigmoidf_(a0.w));
        af[4] = bfc(sigmoidf_(a1.x)); af[5] = bfc(sigmoidf_(a1.y));
        af[6] = bfc(sigmoidf_(a1.z)); af[7] = bfc(sigmoidf_(a1.w));
        const int krow = kk * 32 + q * 8;
#pragma unroll
        for (int ct = 0; ct < 8; ++ct) {
            const int col = ct * 16 + l15;
            short8 bf = *(const short8*)(Wf1T + col * 384 + krow);
            acc[ct] = __builtin_amdgcn_mfma_f32_16x16x32_bf16(af, bf, acc[ct], 0, 0, 0);
        }
    }

#pragma unroll
    for (int ct = 0; ct < 8; ++ct) {
        const int col = ct * 16 + l15;
        const float b = bf1v[col];
#pragma unroll
        for (int r = 0; r < 4; ++r) {
            gbuf[q * 4 + r][col] = bfc(sigmoidf_(acc[ct][r] + b));
        }
    }

    floatx4 acc2[8];
#pragma unroll
    for (int i = 0; i < 8; ++i) acc2[i] = (floatx4)(0.f);
#pragma unroll
    for (int kk = 0; kk < 4; ++kk) {
        const int krow = kk * 32 + q * 8;
        short8 af = *(const short8*)(&gbuf[l15][krow]);
#pragma unroll
        for (int ct = 0; ct < 8; ++ct) {
            const int col = ct * 16 + l15;
            short8 bf = *(const short8*)(Wf2T + col * 128 + krow);
            acc2[ct] = __builtin_amdgcn_mfma_f32_16x16x32_bf16(af, bf, acc2[ct], 0, 0, 0);
        }
    }

#pragma unroll
    for (int ct = 0; ct < 8; ++ct) {
        const int col = ct * 16 + l15;
        const float b = bf2v[col];
#pragma unroll
        for (int r = 0; r < 4; ++r) {
            const int node = nbase + q * 4 + r;
            out[(size_t)node * 128 + col] = softsignf_(acc2[ct][r] + b);
        }
    }
}

extern "C" void kernel_launch(void* const* d_in, const int* in_sizes, int n_in,
                              void* d_out, int out_size, void* d_ws, size_t ws_size,
                              hipStream_t stream)
{
    const float* feat = (const float*)d_in[0];
    const int* rows = (const int*)d_in[1];
    const int* cols = (const int*)d_in[2];
    const float* temb = (const float*)d_in[3];
    const float* Wm1 = (const float*)d_in[4];
    const float* bm1 = (const float*)d_in[5];
    const float* Wm2 = (const float*)d_in[6];
    const float* bm2 = (const float*)d_in[7];
    const float* Wf1 = (const float*)d_in[8];
    const float* bf1 = (const float*)d_in[9];
    const float* Wf2 = (const float*)d_in[10];
    const float* bf2 = (const float*)d_in[11];
    float* out = (float*)d_out;
    float* agg = (float*)d_out;   // aliased: edge stores rows here, node reads row n before writing it

    // Workspace layout (16B-aligned):
    //   Ub     bf16 [10000][128]      2,560,000 B   @ 0
    //   Vb     bf16 [10000][128]      2,560,000 B   @ 2,560,000
    //   WuvT   bf16 [256][128]           65,536 B   @ 5,120,000
    //   W2s    bf16 [128][128] swz       32,768 B   @ 5,185,536
    //   Wf1T   bf16 [128][384]           98,304 B   @ 5,218,304
    //   Wf2T   bf16 [128][128]           32,768 B   @ 5,316,608
    //   ecbin  u16  [10000][160]      3,200,000 B   @ 5,349,376
    //   counts i32  [NN]                 40,000 B   @ 8,549,376
    char* ws = (char*)d_ws;
    short* Ub    = (short*)ws;
    short* Vb    = (short*)(ws + 2560000);
    short* WuvT  = (short*)(ws + 5120000);
    short* W2s   = (short*)(ws + 5185536);
    short* Wf1T  = (short*)(ws + 5218304);
    short* Wf2T  = (short*)(ws + 5316608);
    unsigned short* ecbin = (unsigned short*)(ws + 5349376);
    int* counts  = (int*)(ws + 8549376);

    hipMemsetAsync(counts, 0, NN * sizeof(int), stream);
    prep_all<<<2948, 256, 0, stream>>>(rows, cols, Wm1, Wm2, Wf1, Wf2,
                                       WuvT, W2s, Wf1T, Wf2T, counts, ecbin);
    uv_kernel<<<625, 64, 0, stream>>>(feat, WuvT, bm1, Ub, Vb);

    edge_kernel<<<NN / 4, 256, 0, stream>>>(Ub, Vb, ecbin, counts, W2s, bm2, agg);
    node_kernel<<<625, 64, 0, stream>>>(feat, agg, temb, Wf1T, bf1, Wf2T, bf2, out);
}